// Round 1
// baseline (13714.816 us; speedup 1.0000x reference)
//
#include <hip/hip_runtime.h>
#include <hip/hip_cooperative_groups.h>

namespace cg = cooperative_groups;

#define NB 32       // batch
#define NT 1024     // time
#define NH 512      // hidden
#define NE 256      // embed dim per channel
#define NV0 2048
#define NV1 512
#define G3H 1536    // 3*NH
#define NG 16       // nodes per work group

// ---------------- prep kernels ----------------

__global__ void k_init(const float* __restrict__ hidden, float* __restrict__ buf,
                       int* __restrict__ level_count, int* __restrict__ cursor,
                       int* __restrict__ meta) {
  int i = blockIdx.x * blockDim.x + threadIdx.x;
  if (i < NB * NH) buf[i] = hidden[i];           // buf[0][b][h]
  if (i < 1025) { level_count[i] = 0; cursor[i] = 0; }
  if (i == 0) meta[0] = 0;
}

// in [1536][512] -> out [512][1536]
__global__ void k_transpose(const float* __restrict__ in, float* __restrict__ out) {
  __shared__ float tile[32][33];
  int bx = blockIdx.x;  // k tiles (16)
  int by = blockIdx.y;  // r tiles (48)
  int x = threadIdx.x, y = threadIdx.y;
  #pragma unroll
  for (int j = 0; j < 4; ++j) {
    int r = by * 32 + y + j * 8;
    tile[y + j * 8][x] = in[r * 512 + bx * 32 + x];
  }
  __syncthreads();
  #pragma unroll
  for (int j = 0; j < 4; ++j) {
    int k = bx * 32 + y + j * 8;
    out[k * 1536 + by * 32 + x] = tile[x][y + j * 8];
  }
}

// proj0[v][r] = sum_k emb0[v][k] * W_ih[r][k]        (k < 256)
// proj1[v][r] = sum_k emb1[v][k] * W_ih[r][256+k]
__global__ __launch_bounds__(256) void k_proj(const float* __restrict__ emb0,
                                              const float* __restrict__ emb1,
                                              const float* __restrict__ Wt_ih,
                                              float* __restrict__ proj0,
                                              float* __restrict__ proj1) {
  __shared__ float a[8][NE];
  int g0 = blockIdx.x * 8;
  int tid = threadIdx.x;
  for (int i = tid; i < 8 * NE; i += 256) {
    int v = g0 + (i >> 8);
    int k = i & 255;
    float val = (v < NV0) ? emb0[v * NE + k] : emb1[(v - NV0) * NE + k];
    a[i >> 8][k] = val;
  }
  __syncthreads();
  bool is0 = (g0 < NV0);
  int koff = is0 ? 0 : NE;
  float acc[8][6];
  #pragma unroll
  for (int v = 0; v < 8; ++v)
    #pragma unroll
    for (int j = 0; j < 6; ++j) acc[v][j] = 0.f;
  for (int k = 0; k < NE; ++k) {
    const float* wrow = Wt_ih + (size_t)(k + koff) * G3H;
    float w[6];
    #pragma unroll
    for (int j = 0; j < 6; ++j) w[j] = wrow[tid + j * 256];
    #pragma unroll
    for (int v = 0; v < 8; ++v) {
      float av = a[v][k];
      #pragma unroll
      for (int j = 0; j < 6; ++j) acc[v][j] += av * w[j];
    }
  }
  float* outp = is0 ? (proj0 + (size_t)g0 * G3H) : (proj1 + (size_t)(g0 - NV0) * G3H);
  for (int v = 0; v < 8; ++v)
    for (int j = 0; j < 6; ++j)
      outp[(size_t)v * G3H + tid + j * 256] = acc[v][j];
}

// per-batch dependency levels: lvl[0]=0, lvl[t+1]=lvl[cond[t]]+1; node plevel = lvl[t+1]-1
__global__ void k_levels(const int* __restrict__ cond, int* __restrict__ plv,
                         int* __restrict__ level_count) {
  __shared__ int c_lds[NT];
  __shared__ int lvl[NT + 1];
  int b = blockIdx.x, tid = threadIdx.x;
  for (int i = tid; i < NT; i += blockDim.x) c_lds[i] = cond[b * NT + i];
  __syncthreads();
  if (tid == 0) {
    lvl[0] = 0;
    for (int t = 0; t < NT; ++t) lvl[t + 1] = lvl[c_lds[t]] + 1;
  }
  __syncthreads();
  for (int t = tid; t < NT; t += blockDim.x) {
    int p = lvl[t + 1] - 1;
    plv[b * NT + t] = p;
    atomicAdd(&level_count[p], 1);
  }
}

__global__ void k_scan(const int* __restrict__ level_count, int* __restrict__ level_offset,
                       int* __restrict__ meta) {
  __shared__ int c[1025];
  int tid = threadIdx.x;
  for (int i = tid; i < 1025; i += blockDim.x) c[i] = level_count[i];
  __syncthreads();
  if (tid == 0) {
    int off = 0, Lmax = 0;
    for (int p = 0; p < 1025; ++p) {
      level_offset[p] = off;
      off += c[p];
      if (c[p] > 0) Lmax = p + 1;
    }
    level_offset[1025] = off;
    meta[0] = Lmax;
  }
}

__global__ void k_scatter(const int* __restrict__ plv, const int* __restrict__ level_offset,
                          int* __restrict__ cursor, int* __restrict__ node_list) {
  int id = blockIdx.x * blockDim.x + threadIdx.x;
  if (id >= NB * NT) return;
  int b = id / NT, t = id % NT;
  int p = plv[id];
  int pos = atomicAdd(&cursor[p], 1);
  node_list[level_offset[p] + pos] = (b << 16) | t;
}

// ---------------- recurrence (cooperative, level-parallel) ----------------

__global__ __launch_bounds__(192) void rnn_steps(
    const int* __restrict__ node_list, const int* __restrict__ level_count,
    const int* __restrict__ level_offset, const int* __restrict__ meta,
    const int* __restrict__ cond, const int* __restrict__ tok0, const int* __restrict__ tok1,
    const float* __restrict__ W_hh, const float* __restrict__ proj0,
    const float* __restrict__ proj1, const float* __restrict__ b_ih,
    const float* __restrict__ b_hh, float* __restrict__ buf) {
  cg::grid_group grid = cg::this_grid();
  __shared__ float h_lds[NG][NH];
  __shared__ float pre_r[NG][64], pre_z[NG][64], gin_s[NG][64], ghn_s[NG][64];
  __shared__ int s_b[NG], s_t[NG], s_par[NG], s_k0[NG], s_k1[NG];
  int tid = threadIdx.x;
  int L = meta[0];
  for (int p = 0; p < L; ++p) {
    int n = level_count[p];
    int base = level_offset[p];
    int items = ((n + NG - 1) / NG) << 3;   // groups * 8 h-chunks
    for (int it = blockIdx.x; it < items; it += gridDim.x) {
      int grp = it >> 3, chunk = it & 7;
      int nb = n - grp * NG; if (nb > NG) nb = NG;
      __syncthreads();   // protect LDS reuse across items
      if (tid < NG) {
        int b = 0, t = 0, par = 0, q0 = 0, q1 = 0;
        if (tid < nb) {
          int pk = node_list[base + grp * NG + tid];
          b = pk >> 16; t = pk & 0xFFFF;
          par = cond[b * NT + t];
          q0 = tok0[b * NT + t];
          q1 = tok1[b * NT + t];
        }
        s_b[tid] = b; s_t[tid] = t; s_par[tid] = par; s_k0[tid] = q0; s_k1[tid] = q1;
      }
      __syncthreads();
      for (int i = tid; i < nb * NH; i += 192) {
        int ng = i >> 9, k = i & (NH - 1);
        h_lds[ng][k] = buf[((size_t)s_par[ng] * NB + s_b[ng]) * NH + k];
      }
      __syncthreads();
      {
        int a = tid / 48, wq = tid % 48;
        int ngb = a * 4;
        int rr[4];
        #pragma unroll
        for (int j = 0; j < 4; ++j) {
          int lr = wq * 4 + j;
          rr[j] = (lr >> 6) * NH + chunk * 64 + (lr & 63);
        }
        float acc[4][4];
        #pragma unroll
        for (int i = 0; i < 4; ++i)
          #pragma unroll
          for (int j = 0; j < 4; ++j) acc[i][j] = 0.f;
        for (int k = 0; k < NH; k += 4) {
          float4 wv[4], hv[4];
          #pragma unroll
          for (int j = 0; j < 4; ++j) wv[j] = *(const float4*)(W_hh + (size_t)rr[j] * NH + k);
          #pragma unroll
          for (int i = 0; i < 4; ++i) hv[i] = *(const float4*)(&h_lds[ngb + i][k]);
          #pragma unroll
          for (int i = 0; i < 4; ++i)
            #pragma unroll
            for (int j = 0; j < 4; ++j)
              acc[i][j] += hv[i].x * wv[j].x + hv[i].y * wv[j].y +
                           hv[i].z * wv[j].z + hv[i].w * wv[j].w;
        }
        #pragma unroll
        for (int i = 0; i < 4; ++i) {
          int ng = ngb + i;
          if (ng < nb) {
            #pragma unroll
            for (int j = 0; j < 4; ++j) {
              int lr = wq * 4 + j;
              int g = lr >> 6, hh = lr & 63;
              int r = rr[j];
              float gi = proj0[(size_t)s_k0[ng] * G3H + r] +
                         proj1[(size_t)s_k1[ng] * G3H + r] + b_ih[r];
              float gh = acc[i][j] + b_hh[r];
              if (g == 0)      pre_r[ng][hh] = gi + gh;
              else if (g == 1) pre_z[ng][hh] = gi + gh;
              else           { gin_s[ng][hh] = gi; ghn_s[ng][hh] = gh; }
            }
          }
        }
      }
      __syncthreads();
      for (int i = tid; i < nb * 64; i += 192) {
        int ng = i >> 6, hh = i & 63;
        float rg = 1.f / (1.f + expf(-pre_r[ng][hh]));
        float zg = 1.f / (1.f + expf(-pre_z[ng][hh]));
        float nn = tanhf(gin_s[ng][hh] + rg * ghn_s[ng][hh]);
        float hp = h_lds[ng][chunk * 64 + hh];
        buf[((size_t)(s_t[ng] + 1) * NB + s_b[ng]) * NH + chunk * 64 + hh] =
            (1.f - zg) * nn + zg * hp;
      }
    }
    grid.sync();
  }
}

// ---------------- decode GEMM: C[m][v] = sum_k O[m][k] * W[v][k] + bias[v] ----------------

__global__ __launch_bounds__(256) void k_dec(const float* __restrict__ buf,
                                             const float* __restrict__ W,
                                             const float* __restrict__ bias,
                                             float* __restrict__ out, int N) {
  __shared__ float As[16][68];   // [k][m], 68 keeps 16B alignment + bank spread
  __shared__ float Bs[16][68];   // [k][n]
  int tid = threadIdx.x;
  int n0 = blockIdx.x * 64;
  int m0 = blockIdx.y * 64;
  int tx = tid & 15, ty = tid >> 4;
  int lrow = tid >> 2, lc4 = tid & 3;
  int mA = m0 + lrow;
  // output row m=(b,t) -> buf[(t+1)][b][:]
  const float* Arow = buf + ((size_t)((mA & (NT - 1)) + 1) * NB + (mA >> 10)) * NH;
  const float* Brow = W + (size_t)(n0 + lrow) * NH;
  float acc[4][4];
  #pragma unroll
  for (int i = 0; i < 4; ++i)
    #pragma unroll
    for (int j = 0; j < 4; ++j) acc[i][j] = 0.f;
  for (int kt = 0; kt < NH; kt += 16) {
    float4 av = *(const float4*)(Arow + kt + lc4 * 4);
    float4 bv = *(const float4*)(Brow + kt + lc4 * 4);
    __syncthreads();
    As[lc4 * 4 + 0][lrow] = av.x;
    As[lc4 * 4 + 1][lrow] = av.y;
    As[lc4 * 4 + 2][lrow] = av.z;
    As[lc4 * 4 + 3][lrow] = av.w;
    Bs[lc4 * 4 + 0][lrow] = bv.x;
    Bs[lc4 * 4 + 1][lrow] = bv.y;
    Bs[lc4 * 4 + 2][lrow] = bv.z;
    Bs[lc4 * 4 + 3][lrow] = bv.w;
    __syncthreads();
    #pragma unroll
    for (int k = 0; k < 16; ++k) {
      float4 a4 = *(const float4*)(&As[k][ty * 4]);
      float4 b4 = *(const float4*)(&Bs[k][tx * 4]);
      #pragma unroll
      for (int i = 0; i < 4; ++i) {
        float ai = (i == 0) ? a4.x : (i == 1) ? a4.y : (i == 2) ? a4.z : a4.w;
        acc[i][0] += ai * b4.x;
        acc[i][1] += ai * b4.y;
        acc[i][2] += ai * b4.z;
        acc[i][3] += ai * b4.w;
      }
    }
  }
  float4 bb = *(const float4*)(bias + n0 + tx * 4);
  #pragma unroll
  for (int i = 0; i < 4; ++i) {
    int m = m0 + ty * 4 + i;
    float4 o;
    o.x = acc[i][0] + bb.x;
    o.y = acc[i][1] + bb.y;
    o.z = acc[i][2] + bb.z;
    o.w = acc[i][3] + bb.w;
    *(float4*)(out + (size_t)m * N + n0 + tx * 4) = o;
  }
}

__global__ void k_tail(const float* __restrict__ buf, float* __restrict__ out) {
  int i = blockIdx.x * blockDim.x + threadIdx.x;
  if (i < NB * NH) out[i] = buf[(size_t)NT * NB * NH + i];
}

// ---------------- launch ----------------

extern "C" void kernel_launch(void* const* d_in, const int* in_sizes, int n_in,
                              void* d_out, int out_size, void* d_ws, size_t ws_size,
                              hipStream_t stream) {
  const int*   tokens0    = (const int*)d_in[0];
  const int*   tokens1    = (const int*)d_in[1];
  const int*   conditions = (const int*)d_in[2];
  const float* hidden     = (const float*)d_in[3];
  const float* emb0       = (const float*)d_in[4];
  const float* emb1       = (const float*)d_in[5];
  const float* W_ih       = (const float*)d_in[6];
  const float* W_hh       = (const float*)d_in[7];
  const float* b_ih       = (const float*)d_in[8];
  const float* b_hh       = (const float*)d_in[9];
  const float* dec0_W     = (const float*)d_in[10];
  const float* dec0_b     = (const float*)d_in[11];
  const float* dec1_W     = (const float*)d_in[12];
  const float* dec1_b     = (const float*)d_in[13];

  float* ws    = (float*)d_ws;
  float* proj0 = ws;                       // 2048*1536
  float* proj1 = ws + 3145728;             // 512*1536
  float* Wt_ih = ws + 3932160;             // 512*1536
  float* buf   = ws + 4718592;             // 1025*32*512
  int* iws          = (int*)(ws + 21512192);
  int* plv          = iws;                 // 32768
  int* level_count  = iws + 32768;         // 1025
  int* level_offset = iws + 33793;         // 1026
  int* cursor       = iws + 34819;         // 1025
  int* meta         = iws + 35844;         // 8
  int* node_list    = iws + 35852;         // 32768

  float* out0 = (float*)d_out;
  float* out1 = out0 + (size_t)NB * NT * NV0;
  float* outT = out1 + (size_t)NB * NT * NV1;

  k_init<<<64, 256, 0, stream>>>(hidden, buf, level_count, cursor, meta);
  k_transpose<<<dim3(16, 48), dim3(32, 8), 0, stream>>>(W_ih, Wt_ih);
  k_proj<<<320, 256, 0, stream>>>(emb0, emb1, Wt_ih, proj0, proj1);
  k_levels<<<32, 256, 0, stream>>>(conditions, plv, level_count);
  k_scan<<<1, 256, 0, stream>>>(level_count, level_offset, meta);
  k_scatter<<<128, 256, 0, stream>>>(plv, level_offset, cursor, node_list);

  int maxb = 0;
  if (hipOccupancyMaxActiveBlocksPerMultiprocessor(&maxb, (const void*)rnn_steps, 192, 0) !=
          hipSuccess || maxb < 1)
    maxb = 1;
  int nwg = maxb * 256;
  if (nwg > 512) nwg = 512;
  {
    const int* a0 = node_list; const int* a1 = level_count; const int* a2 = level_offset;
    const int* a3 = meta; const int* a4 = conditions; const int* a5 = tokens0;
    const int* a6 = tokens1;
    const float* a7 = W_hh; const float* a8 = proj0; const float* a9 = proj1;
    const float* a10 = b_ih; const float* a11 = b_hh; float* a12 = buf;
    void* kargs[] = { &a0, &a1, &a2, &a3, &a4, &a5, &a6, &a7, &a8, &a9, &a10, &a11, &a12 };
    hipLaunchCooperativeKernel((const void*)rnn_steps, dim3(nwg), dim3(192), kargs, 0, stream);
  }

  k_dec<<<dim3(NV0 / 64, (NB * NT) / 64), 256, 0, stream>>>(buf, dec0_W, dec0_b, out0, NV0);
  k_dec<<<dim3(NV1 / 64, (NB * NT) / 64), 256, 0, stream>>>(buf, dec1_W, dec1_b, out1, NV1);
  k_tail<<<64, 256, 0, stream>>>(buf, outT);
}

// Round 2
// 9800.450 us; speedup vs baseline: 1.3994x; 1.3994x over previous
//
#include <hip/hip_runtime.h>
#include <hip/hip_cooperative_groups.h>

namespace cg = cooperative_groups;

#define NB 32
#define NT 1024
#define NH 512
#define NE 256
#define NV0 2048
#define NV1 512
#define G3H 1536

typedef __attribute__((ext_vector_type(8))) short bf16x8;
typedef __attribute__((ext_vector_type(4))) float f32x4;
typedef unsigned short u16;

__device__ __forceinline__ u16 bf16_hi(float x) {
  unsigned u = __float_as_uint(x);
  unsigned r = (u + 0x7FFF + ((u >> 16) & 1)) >> 16;
  return (u16)r;
}
__device__ __forceinline__ float bf16_f(u16 h) {
  return __uint_as_float(((unsigned)h) << 16);
}

// ---------------- prep ----------------

__global__ void k_init(const float* __restrict__ hidden, u16* __restrict__ bufh,
                       u16* __restrict__ bufl) {
  int i = blockIdx.x * blockDim.x + threadIdx.x;
  if (i < NB * NH) {
    float v = hidden[i];
    u16 hi = bf16_hi(v);
    float lo = v - bf16_f(hi);
    bufh[i] = hi;
    bufl[i] = bf16_hi(lo);
  }
}

// in [1536][512] -> out [512][1536]
__global__ void k_transpose(const float* __restrict__ in, float* __restrict__ out) {
  __shared__ float tile[32][33];
  int bx = blockIdx.x, by = blockIdx.y;
  int x = threadIdx.x, y = threadIdx.y;
  #pragma unroll
  for (int j = 0; j < 4; ++j) {
    int r = by * 32 + y + j * 8;
    tile[y + j * 8][x] = in[r * 512 + bx * 32 + x];
  }
  __syncthreads();
  #pragma unroll
  for (int j = 0; j < 4; ++j) {
    int k = bx * 32 + y + j * 8;
    out[k * 1536 + by * 32 + x] = tile[x][y + j * 8];
  }
}

__global__ __launch_bounds__(256) void k_proj(const float* __restrict__ emb0,
                                              const float* __restrict__ emb1,
                                              const float* __restrict__ Wt_ih,
                                              float* __restrict__ proj0,
                                              float* __restrict__ proj1) {
  __shared__ float a[8][NE];
  int g0 = blockIdx.x * 8;
  int tid = threadIdx.x;
  for (int i = tid; i < 8 * NE; i += 256) {
    int v = g0 + (i >> 8);
    int k = i & 255;
    float val = (v < NV0) ? emb0[v * NE + k] : emb1[(v - NV0) * NE + k];
    a[i >> 8][k] = val;
  }
  __syncthreads();
  bool is0 = (g0 < NV0);
  int koff = is0 ? 0 : NE;
  float acc[8][6];
  #pragma unroll
  for (int v = 0; v < 8; ++v)
    #pragma unroll
    for (int j = 0; j < 6; ++j) acc[v][j] = 0.f;
  for (int k = 0; k < NE; ++k) {
    const float* wrow = Wt_ih + (size_t)(k + koff) * G3H;
    float w[6];
    #pragma unroll
    for (int j = 0; j < 6; ++j) w[j] = wrow[tid + j * 256];
    #pragma unroll
    for (int v = 0; v < 8; ++v) {
      float av = a[v][k];
      #pragma unroll
      for (int j = 0; j < 6; ++j) acc[v][j] += av * w[j];
    }
  }
  float* outp = is0 ? (proj0 + (size_t)g0 * G3H) : (proj1 + (size_t)(g0 - NV0) * G3H);
  for (int v = 0; v < 8; ++v)
    for (int j = 0; j < 6; ++j)
      outp[(size_t)v * G3H + tid + j * 256] = acc[v][j];
}

// W_hh [1536][512] f32 -> Wf hi/lo bf16 in B-fragment-major layout.
// itemrow = (hh>>5)*96 + g*32 + (hh&31);  phys = ((itemrow>>4)*64 + (k>>3))*128
//          + (itemrow&15)*8 + (k&7)
__global__ void k_wsplit(const float* __restrict__ W_hh, u16* __restrict__ Wfh,
                         u16* __restrict__ Wfl) {
  int idx = blockIdx.x * blockDim.x + threadIdx.x;
  if (idx >= G3H * NH) return;
  int row = idx >> 9, k = idx & 511;
  int g = row >> 9, hh = row & 511;
  int itemrow = (hh >> 5) * 96 + g * 32 + (hh & 31);
  size_t phys = ((size_t)((itemrow >> 4) * 64 + (k >> 3))) * 128 + (itemrow & 15) * 8 + (k & 7);
  float v = W_hh[idx];
  u16 hi = bf16_hi(v);
  float lo = v - bf16_f(hi);
  Wfh[phys] = hi;
  Wfl[phys] = bf16_hi(lo);
}

// deterministic level computation
__global__ void k_levels(const int* __restrict__ cond, int* __restrict__ plv,
                         int* __restrict__ cntb) {
  __shared__ int c_lds[NT];
  __shared__ int lvl[NT + 1];
  __shared__ int cnt[NT + 1];
  int b = blockIdx.x, tid = threadIdx.x;
  for (int i = tid; i < NT; i += 256) c_lds[i] = cond[b * NT + i];
  for (int i = tid; i <= NT; i += 256) cnt[i] = 0;
  __syncthreads();
  if (tid == 0) {
    lvl[0] = 0;
    for (int t = 0; t < NT; ++t) {
      lvl[t + 1] = lvl[c_lds[t]] + 1;
      cnt[lvl[t + 1] - 1]++;
    }
  }
  __syncthreads();
  for (int t = tid; t < NT; t += 256) plv[b * NT + t] = lvl[t + 1] - 1;
  for (int p = tid; p <= NT; p += 256) cntb[p * NB + b] = cnt[p];
}

__global__ void k_scan(const int* __restrict__ cntb, int* __restrict__ level_offset,
                       int* __restrict__ startpb, int* __restrict__ level_n,
                       int* __restrict__ meta) {
  __shared__ int rowsum[NT + 1];
  int tid = threadIdx.x;
  for (int p = tid; p <= NT; p += 1024) {
    int s = 0;
    for (int b = 0; b < NB; ++b) s += cntb[p * NB + b];
    rowsum[p] = s;
    level_n[p] = s;
  }
  __syncthreads();
  if (tid == 0) {
    int off = 0, Lmax = 0;
    for (int p = 0; p <= NT; ++p) {
      level_offset[p] = off;
      if (rowsum[p] > 0) Lmax = p + 1;
      off += rowsum[p];
    }
    meta[0] = Lmax;
  }
  __syncthreads();
  for (int p = tid; p <= NT; p += 1024) {
    int off = level_offset[p];
    for (int b = 0; b < NB; ++b) {
      startpb[p * NB + b] = off;
      off += cntb[p * NB + b];
    }
  }
}

__global__ void k_scatter(const int* __restrict__ plv, const int* __restrict__ startpb,
                          int* __restrict__ node_list) {
  __shared__ int cur[NT + 1];
  int b = blockIdx.x, tid = threadIdx.x;
  for (int p = tid; p <= NT; p += 256) cur[p] = startpb[p * NB + b];
  __syncthreads();
  if (tid == 0) {
    for (int t = 0; t < NT; ++t) {
      int p = plv[b * NT + t];
      node_list[cur[p]++] = (b << 16) | t;
    }
  }
}

// ---------------- recurrence: level-parallel MFMA bf16 3-split ----------------

__global__ __launch_bounds__(192) void rnn_steps(
    const int* __restrict__ node_list, const int* __restrict__ level_n,
    const int* __restrict__ level_offset, const int* __restrict__ meta,
    const int* __restrict__ cond, const int* __restrict__ tok0, const int* __restrict__ tok1,
    const u16* __restrict__ Wfh, const u16* __restrict__ Wfl,
    const float* __restrict__ proj0, const float* __restrict__ proj1,
    const float* __restrict__ b_ih, const float* __restrict__ b_hh,
    u16* __restrict__ bufh, u16* __restrict__ bufl) {
  cg::grid_group grid = cg::this_grid();
  __shared__ unsigned char hds_h[16 * 1024];
  __shared__ unsigned char hds_l[16 * 1024];
  __shared__ float pre[3][16][32];
  __shared__ int s_tb[16], s_par[16], s_k0[16], s_k1[16];
  int tid = threadIdx.x;
  int w = tid >> 6, lane = tid & 63;
  int q = lane >> 4, m = lane & 15;
  int L = meta[0];
  for (int p = 0; p < L; ++p) {
    int n = level_n[p];
    int base = level_offset[p];
    int items = ((n + 15) >> 4) << 4;   // node-groups * 16 chunks
    for (int it = blockIdx.x; it < items; it += gridDim.x) {
      int grp = it >> 4, chunk = it & 15;
      int nb = n - grp * 16; if (nb > 16) nb = 16;
      __syncthreads();   // protect LDS across items
      if (tid < 16) {
        int b = 0, t = -1, par = 0, q0 = 0, q1 = 0;
        if (tid < nb) {
          int pk = node_list[base + grp * 16 + tid];
          b = pk >> 16; t = pk & 0xFFFF;
          par = cond[b * NT + t];
          q0 = tok0[b * NT + t];
          q1 = tok1[b * NT + t];
        }
        s_tb[tid] = (t + 1) * NB + b;
        s_par[tid] = par * NB + b;
        s_k0[tid] = q0; s_k1[tid] = q1;
      }
      __syncthreads();
      // stage parent h (hi/lo bf16) into LDS, XOR-swizzled 16B slots
      for (int i = tid; i < 16 * 64; i += 192) {
        int r = i >> 6, c = i & 63;
        size_t src = (size_t)s_par[r] * NH + c * 8;
        int dst = r * 1024 + ((c * 16) ^ ((r & 7) << 4));
        *(uint4*)(hds_h + dst) = *(const uint4*)(bufh + src);
        *(uint4*)(hds_l + dst) = *(const uint4*)(bufl + src);
      }
      __syncthreads();
      // MFMA: 3 waves x 2 N-tiles each; C[16 nodes][96 rows], K=512
      {
        f32x4 acc0 = {0.f, 0.f, 0.f, 0.f}, acc1 = {0.f, 0.f, 0.f, 0.f};
        int arow = m * 1024;
        int aswz = (m & 7) << 4;
        size_t btile = (size_t)(chunk * 6 + w * 2) * 64;
        #pragma unroll 4
        for (int s = 0; s < 16; ++s) {
          int ab = arow + (((s * 64) + (q * 16)) ^ aswz);
          bf16x8 ah = *(const bf16x8*)(hds_h + ab);
          bf16x8 al = *(const bf16x8*)(hds_l + ab);
          size_t b0 = (btile + s * 4 + q) * 128 + m * 8;
          size_t b1 = b0 + 64 * 128;
          bf16x8 bh0 = *(const bf16x8*)(Wfh + b0);
          bf16x8 bl0 = *(const bf16x8*)(Wfl + b0);
          bf16x8 bh1 = *(const bf16x8*)(Wfh + b1);
          bf16x8 bl1 = *(const bf16x8*)(Wfl + b1);
          acc0 = __builtin_amdgcn_mfma_f32_16x16x32_bf16(ah, bh0, acc0, 0, 0, 0);
          acc0 = __builtin_amdgcn_mfma_f32_16x16x32_bf16(ah, bl0, acc0, 0, 0, 0);
          acc0 = __builtin_amdgcn_mfma_f32_16x16x32_bf16(al, bh0, acc0, 0, 0, 0);
          acc1 = __builtin_amdgcn_mfma_f32_16x16x32_bf16(ah, bh1, acc1, 0, 0, 0);
          acc1 = __builtin_amdgcn_mfma_f32_16x16x32_bf16(ah, bl1, acc1, 0, 0, 0);
          acc1 = __builtin_amdgcn_mfma_f32_16x16x32_bf16(al, bh1, acc1, 0, 0, 0);
        }
        // D layout: col=lane&15 (row dim of W), row=(lane>>4)*4+i (node)
        #pragma unroll
        for (int cc = 0; cc < 2; ++cc) {
          int rloc = (w * 2 + cc) * 16 + m;
          int g = rloc >> 5, u = rloc & 31;
          #pragma unroll
          for (int i2 = 0; i2 < 4; ++i2) {
            int node = q * 4 + i2;
            pre[g][node][u] = cc ? acc1[i2] : acc0[i2];
          }
        }
      }
      __syncthreads();
      // nonlinearity + state write (32 hh per node)
      for (int i = tid; i < nb * 32; i += 192) {
        int node = i >> 5, u = i & 31;
        int k = chunk * 32 + u;
        const float* p0 = proj0 + (size_t)s_k0[node] * G3H;
        const float* p1 = proj1 + (size_t)s_k1[node] * G3H;
        float gr = p0[k] + p1[k] + b_ih[k] + b_hh[k] + pre[0][node][u];
        float gz = p0[NH + k] + p1[NH + k] + b_ih[NH + k] + b_hh[NH + k] + pre[1][node][u];
        float gin = p0[2 * NH + k] + p1[2 * NH + k] + b_ih[2 * NH + k];
        float ghn = pre[2][node][u] + b_hh[2 * NH + k];
        float r = 1.f / (1.f + expf(-gr));
        float z = 1.f / (1.f + expf(-gz));
        float nn = tanhf(gin + r * ghn);
        int hb = node * 1024 + ((k * 2) ^ ((node & 7) << 4));
        float hp = bf16_f(*(const u16*)(hds_h + hb)) + bf16_f(*(const u16*)(hds_l + hb));
        float hn = (1.f - z) * nn + z * hp;
        u16 hi = bf16_hi(hn);
        float lo = hn - bf16_f(hi);
        size_t o = (size_t)s_tb[node] * NH + k;
        bufh[o] = hi;
        bufl[o] = bf16_hi(lo);
      }
    }
    grid.sync();
  }
}

// ---------------- decode GEMM (f32 compute, bf16 hi/lo A) ----------------

__global__ __launch_bounds__(256) void k_dec(const u16* __restrict__ bufh,
                                             const u16* __restrict__ bufl,
                                             const float* __restrict__ W,
                                             const float* __restrict__ bias,
                                             float* __restrict__ out, int N) {
  __shared__ float As[16][68];
  __shared__ float Bs[16][68];
  int tid = threadIdx.x;
  int n0 = blockIdx.x * 64;
  int m0 = blockIdx.y * 64;
  int tx = tid & 15, ty = tid >> 4;
  int lrow = tid >> 2, lc4 = tid & 3;
  int mA = m0 + lrow;
  size_t tbA = (size_t)((mA & (NT - 1)) + 1) * NB + (mA >> 10);
  const u16* Ah = bufh + tbA * NH;
  const u16* Al = bufl + tbA * NH;
  const float* Brow = W + (size_t)(n0 + lrow) * NH;
  float acc[4][4];
  #pragma unroll
  for (int i = 0; i < 4; ++i)
    #pragma unroll
    for (int j = 0; j < 4; ++j) acc[i][j] = 0.f;
  for (int kt = 0; kt < NH; kt += 16) {
    uint2 th = *(const uint2*)(Ah + kt + lc4 * 4);
    uint2 tl = *(const uint2*)(Al + kt + lc4 * 4);
    float4 bv = *(const float4*)(Brow + kt + lc4 * 4);
    __syncthreads();
    As[lc4 * 4 + 0][lrow] = bf16_f((u16)th.x) + bf16_f((u16)tl.x);
    As[lc4 * 4 + 1][lrow] = bf16_f((u16)(th.x >> 16)) + bf16_f((u16)(tl.x >> 16));
    As[lc4 * 4 + 2][lrow] = bf16_f((u16)th.y) + bf16_f((u16)tl.y);
    As[lc4 * 4 + 3][lrow] = bf16_f((u16)(th.y >> 16)) + bf16_f((u16)(tl.y >> 16));
    Bs[lc4 * 4 + 0][lrow] = bv.x;
    Bs[lc4 * 4 + 1][lrow] = bv.y;
    Bs[lc4 * 4 + 2][lrow] = bv.z;
    Bs[lc4 * 4 + 3][lrow] = bv.w;
    __syncthreads();
    #pragma unroll
    for (int k = 0; k < 16; ++k) {
      float4 a4 = *(const float4*)(&As[k][ty * 4]);
      float4 b4 = *(const float4*)(&Bs[k][tx * 4]);
      #pragma unroll
      for (int i = 0; i < 4; ++i) {
        float ai = (i == 0) ? a4.x : (i == 1) ? a4.y : (i == 2) ? a4.z : a4.w;
        acc[i][0] += ai * b4.x;
        acc[i][1] += ai * b4.y;
        acc[i][2] += ai * b4.z;
        acc[i][3] += ai * b4.w;
      }
    }
  }
  float4 bb = *(const float4*)(bias + n0 + tx * 4);
  #pragma unroll
  for (int i = 0; i < 4; ++i) {
    int mm = m0 + ty * 4 + i;
    float4 o;
    o.x = acc[i][0] + bb.x;
    o.y = acc[i][1] + bb.y;
    o.z = acc[i][2] + bb.z;
    o.w = acc[i][3] + bb.w;
    *(float4*)(out + (size_t)mm * N + n0 + tx * 4) = o;
  }
}

__global__ void k_tail(const u16* __restrict__ bufh, const u16* __restrict__ bufl,
                       float* __restrict__ out) {
  int i = blockIdx.x * blockDim.x + threadIdx.x;
  if (i < NB * NH) {
    size_t idx = (size_t)NT * NB * NH + i;
    out[i] = bf16_f(bufh[idx]) + bf16_f(bufl[idx]);
  }
}

// ---------------- launch ----------------

extern "C" void kernel_launch(void* const* d_in, const int* in_sizes, int n_in,
                              void* d_out, int out_size, void* d_ws, size_t ws_size,
                              hipStream_t stream) {
  const int*   tokens0    = (const int*)d_in[0];
  const int*   tokens1    = (const int*)d_in[1];
  const int*   conditions = (const int*)d_in[2];
  const float* hidden     = (const float*)d_in[3];
  const float* emb0       = (const float*)d_in[4];
  const float* emb1       = (const float*)d_in[5];
  const float* W_ih       = (const float*)d_in[6];
  const float* W_hh       = (const float*)d_in[7];
  const float* b_ih       = (const float*)d_in[8];
  const float* b_hh       = (const float*)d_in[9];
  const float* dec0_W     = (const float*)d_in[10];
  const float* dec0_b     = (const float*)d_in[11];
  const float* dec1_W     = (const float*)d_in[12];
  const float* dec1_b     = (const float*)d_in[13];

  char* wsb = (char*)d_ws;
  float* proj0 = (float*)wsb;                      // 2048*1536 f32 = 12,582,912 B
  float* proj1 = (float*)(wsb + 12582912);         // 512*1536 f32  =  3,145,728 B
  float* Wt_ih = (float*)(wsb + 15728640);         // 512*1536 f32  =  3,145,728 B
  u16*   bufh  = (u16*)(wsb + 18874368);           // 1025*32*512 u16 = 33,587,200 B
  u16*   bufl  = (u16*)(wsb + 52461568);           // 33,587,200 B
  u16*   Wfh   = (u16*)(wsb + 86048768);           // 1536*512 u16 = 1,572,864 B
  u16*   Wfl   = (u16*)(wsb + 87621632);           // 1,572,864 B
  int*   iws   = (int*)(wsb + 89194496);
  int* plv          = iws;                 // 32768
  int* cntb         = iws + 32768;         // 1025*32 = 32800
  int* level_offset = iws + 65568;         // 1026
  int* startpb      = iws + 66594;         // 32800
  int* level_n      = iws + 99394;         // 1025
  int* meta         = iws + 100419;        // 8
  int* node_list    = iws + 100427;        // 32768

  float* out0 = (float*)d_out;
  float* out1 = out0 + (size_t)NB * NT * NV0;
  float* outT = out1 + (size_t)NB * NT * NV1;

  k_init<<<64, 256, 0, stream>>>(hidden, bufh, bufl);
  k_transpose<<<dim3(16, 48), dim3(32, 8), 0, stream>>>(W_ih, Wt_ih);
  k_proj<<<320, 256, 0, stream>>>(emb0, emb1, Wt_ih, proj0, proj1);
  k_wsplit<<<3072, 256, 0, stream>>>(W_hh, Wfh, Wfl);
  k_levels<<<32, 256, 0, stream>>>(conditions, plv, cntb);
  k_scan<<<1, 1024, 0, stream>>>(cntb, level_offset, startpb, level_n, meta);
  k_scatter<<<32, 256, 0, stream>>>(plv, startpb, node_list);

  int maxb = 0;
  if (hipOccupancyMaxActiveBlocksPerMultiprocessor(&maxb, (const void*)rnn_steps, 192, 0) !=
          hipSuccess || maxb < 1)
    maxb = 1;
  int nwg = maxb * 256;
  if (nwg > 1024) nwg = 1024;
  {
    const int* a0 = node_list; const int* a1 = level_n; const int* a2 = level_offset;
    const int* a3 = meta; const int* a4 = conditions; const int* a5 = tokens0;
    const int* a6 = tokens1;
    const u16* a7 = Wfh; const u16* a8 = Wfl;
    const float* a9 = proj0; const float* a10 = proj1;
    const float* a11 = b_ih; const float* a12 = b_hh;
    u16* a13 = bufh; u16* a14 = bufl;
    void* kargs[] = { &a0, &a1, &a2, &a3, &a4, &a5, &a6, &a7, &a8, &a9, &a10,
                      &a11, &a12, &a13, &a14 };
    hipLaunchCooperativeKernel((const void*)rnn_steps, dim3(nwg), dim3(192), kargs, 0, stream);
  }

  k_dec<<<dim3(NV0 / 64, (NB * NT) / 64), 256, 0, stream>>>(bufh, bufl, dec0_W, dec0_b, out0, NV0);
  k_dec<<<dim3(NV1 / 64, (NB * NT) / 64), 256, 0, stream>>>(bufh, bufl, dec1_W, dec1_b, out1, NV1);
  k_tail<<<64, 256, 0, stream>>>(bufh, bufl, outT);
}